// Round 1
// baseline (1074.768 us; speedup 1.0000x reference)
//
#include <hip/hip_runtime.h>
#include <hip/hip_bf16.h>
#include <cstdint>

// ---------------------------------------------------------------------------
// RNN_11828339933262: h = x @ w_in^T + b_in ; s_t = tanh(s_{t-1} @ W_n + h_t)
//                     y = rmsnorm(s) * norm_weight ; out = y @ w_out^T
// B=4 S=2048 D=2048 N_HEADS=32 HD=64.  All I/O f32; internal GEMMs bf16 MFMA
// (2% absmax threshold; recurrence is contracting so bf16 error doesn't grow).
// ---------------------------------------------------------------------------

typedef short bf16x8 __attribute__((ext_vector_type(8)));   // 8 bf16 = 4 VGPRs
typedef float f32x4 __attribute__((ext_vector_type(4)));

#define GLD16(gp, lp)                                                          \
  __builtin_amdgcn_global_load_lds(                                            \
      (const __attribute__((address_space(1))) void*)(gp),                     \
      (__attribute__((address_space(3))) void*)(lp), 16, 0, 0)

// ---------------------------- f32 -> bf16 convert --------------------------
__global__ __launch_bounds__(256) void cvt_f32_bf16(
    const float* __restrict__ in, __hip_bfloat16* __restrict__ out, int n4) {
  int i = blockIdx.x * 256 + threadIdx.x;
  if (i >= n4) return;
  float4 v = ((const float4*)in)[i];
  __hip_bfloat16 a = __float2bfloat16(v.x);
  __hip_bfloat16 b = __float2bfloat16(v.y);
  __hip_bfloat16 c = __float2bfloat16(v.z);
  __hip_bfloat16 d = __float2bfloat16(v.w);
  ushort4 p;
  p.x = *(unsigned short*)&a; p.y = *(unsigned short*)&b;
  p.z = *(unsigned short*)&c; p.w = *(unsigned short*)&d;
  ((ushort4*)out)[i] = p;
}

// ------------------------------- NT GEMM ------------------------------------
// C[M][N] = sum_k A[m][k]*B[n][k] (+bias[n]).  A,B bf16 row-major K-contig.
// 128x128 block tile, BK=32, 256 threads = 4 waves in 2x2, each wave 64x64
// (4x4 tiles of mfma_f32_16x16x32_bf16).  m97 structure: global_load_lds
// width-16 staging, 2-barrier K-loop.
__global__ __launch_bounds__(256) void gemm_nt(
    const __hip_bfloat16* __restrict__ A, const __hip_bfloat16* __restrict__ B,
    const float* __restrict__ bias, float* __restrict__ C,
    int M, int N, int K) {
  __shared__ __hip_bfloat16 As[128 * 32];
  __shared__ __hip_bfloat16 Bs[128 * 32];
  const int tid  = threadIdx.x;
  const int lane = tid & 63;
  const int wave = tid >> 6;
  const int wm = wave >> 1, wn = wave & 1;
  const long bm = (long)blockIdx.y * 128;
  const long bn = (long)blockIdx.x * 128;

  // Staging: 512 16B-chunks per tile; chunk c -> row c>>2, kcol (c&3)*8.
  // Chunks are handed out so each wave's 64 lanes cover a contiguous chunk
  // range (global_load_lds requires wave-uniform LDS base + lane*16).
  const int c0 = tid, c1 = tid + 256;
  const int r0 = c0 >> 2, k0 = (c0 & 3) * 8;
  const int r1 = c1 >> 2, k1 = (c1 & 3) * 8;
  __hip_bfloat16* lA0 = &As[(wave * 64) * 8];
  __hip_bfloat16* lA1 = &As[(256 + wave * 64) * 8];
  __hip_bfloat16* lB0 = &Bs[(wave * 64) * 8];
  __hip_bfloat16* lB1 = &Bs[(256 + wave * 64) * 8];
  const __hip_bfloat16* gA0 = A + (bm + r0) * (long)K + k0;
  const __hip_bfloat16* gA1 = A + (bm + r1) * (long)K + k1;
  const __hip_bfloat16* gB0 = B + (bn + r0) * (long)K + k0;
  const __hip_bfloat16* gB1 = B + (bn + r1) * (long)K + k1;

  // Fragment addressing (verified m89/m91): A[m=lane&15][k=(lane>>4)*8+j]
  const int fr = lane & 15;
  const int fk = (lane >> 4) * 8;

  f32x4 acc[4][4];
#pragma unroll
  for (int i = 0; i < 4; i++)
#pragma unroll
    for (int j = 0; j < 4; j++) acc[i][j] = {0.f, 0.f, 0.f, 0.f};

  for (int kt = 0; kt < K; kt += 32) {
    __syncthreads();               // previous iter's fragment reads done
    GLD16(gA0 + kt, lA0);
    GLD16(gA1 + kt, lA1);
    GLD16(gB0 + kt, lB0);
    GLD16(gB1 + kt, lB1);
    __syncthreads();               // staging visible to all waves
    bf16x8 af[4], bfr[4];
#pragma unroll
    for (int t = 0; t < 4; t++)
      af[t] = *(const bf16x8*)&As[(wm * 64 + t * 16 + fr) * 32 + fk];
#pragma unroll
    for (int t = 0; t < 4; t++)
      bfr[t] = *(const bf16x8*)&Bs[(wn * 64 + t * 16 + fr) * 32 + fk];
#pragma unroll
    for (int i = 0; i < 4; i++)
#pragma unroll
      for (int j = 0; j < 4; j++)
        acc[i][j] = __builtin_amdgcn_mfma_f32_16x16x32_bf16(
            af[i], bfr[j], acc[i][j], 0, 0, 0);
  }

  // C/D layout (verified m89/m91): col = lane&15, row = (lane>>4)*4 + reg.
  const int cr = (lane >> 4) * 4;
  const int cc = lane & 15;
#pragma unroll
  for (int j = 0; j < 4; j++) {
    const long n = bn + wn * 64 + j * 16 + cc;
    const float bv = bias ? bias[n] : 0.0f;
#pragma unroll
    for (int i = 0; i < 4; i++) {
      const long m = bm + wm * 64 + i * 16 + cr;
#pragma unroll
      for (int r = 0; r < 4; r++)
        C[(m + r) * (long)N + n] = acc[i][j][r] + bv;
    }
  }
}

// ------------------------------- RNN scan -----------------------------------
// One wave per (batch, head) chain: lane k owns output k. W column W[h][k]
// resident in 64 VGPRs; state broadcast via 64-float LDS buffer (same-address
// ds_read_b128 = conflict-free broadcast). In-place on h: reads x_t window of
// 8 steps ahead, overwrites with s_t.
__device__ __forceinline__ float tanh_fast(float z) {
  float e = __expf(2.0f * z);                       // inf for large z is fine
  return 1.0f - 2.0f * __builtin_amdgcn_rcpf(e + 1.0f);  // -> +/-1 at extremes
}

__global__ __launch_bounds__(64) void scan_kernel(
    const float* __restrict__ Wst, float* __restrict__ h) {
  const int b = blockIdx.x >> 5;    // 0..3
  const int n = blockIdx.x & 31;    // 0..31
  const int lane = threadIdx.x;     // 0..63
  const float* Wn = Wst + n * 4096; // W[n][h][k], k contiguous
  float w[64];
#pragma unroll
  for (int i = 0; i < 64; i++) w[i] = Wn[i * 64 + lane];  // column k=lane

  __shared__ float s_lds[64];
  s_lds[lane] = 0.0f;
  __syncthreads();

  float* hp = h + ((size_t)b * 2048) * 2048 + n * 64 + lane;  // t-stride 2048
  for (int t0 = 0; t0 < 2048; t0 += 8) {
    float xr[8];
#pragma unroll
    for (int i = 0; i < 8; i++) xr[i] = hp[(size_t)(t0 + i) * 2048];
#pragma unroll
    for (int i = 0; i < 8; i++) {
      float a0 = xr[i], a1 = 0.f, a2 = 0.f, a3 = 0.f;
#pragma unroll
      for (int q = 0; q < 64; q += 4) {
        float4 s4 = *(const float4*)&s_lds[q];
        a0 = fmaf(s4.x, w[q],     a0);
        a1 = fmaf(s4.y, w[q + 1], a1);
        a2 = fmaf(s4.z, w[q + 2], a2);
        a3 = fmaf(s4.w, w[q + 3], a3);
      }
      float sn = tanh_fast((a0 + a1) + (a2 + a3));
      s_lds[lane] = sn;            // write depends on all reads -> no WAR race
      __syncthreads();             // make visible before next step's reads
      hp[(size_t)(t0 + i) * 2048] = sn;
    }
  }
}

// --------------------------- RMSNorm -> bf16 --------------------------------
__global__ __launch_bounds__(256) void rmsnorm_to_bf16(
    const float* __restrict__ Y, const float* __restrict__ g,
    __hip_bfloat16* __restrict__ O) {
  const long row = blockIdx.x;
  const float* yr = Y + row * 2048;
  const int tid = threadIdx.x;
  float4 v0 = ((const float4*)yr)[tid * 2];
  float4 v1 = ((const float4*)yr)[tid * 2 + 1];
  float ss = v0.x * v0.x + v0.y * v0.y + v0.z * v0.z + v0.w * v0.w +
             v1.x * v1.x + v1.y * v1.y + v1.z * v1.z + v1.w * v1.w;
#pragma unroll
  for (int off = 32; off > 0; off >>= 1) ss += __shfl_down(ss, off);
  __shared__ float red[4];
  if ((tid & 63) == 0) red[tid >> 6] = ss;
  __syncthreads();
  float inv = rsqrtf((red[0] + red[1] + red[2] + red[3]) * (1.0f / 2048.0f)
                     + 1e-6f);
  float4 g0 = ((const float4*)(g + tid * 8))[0];
  float4 g1 = ((const float4*)(g + tid * 8))[1];
  float ov[8] = {v0.x * inv * g0.x, v0.y * inv * g0.y,
                 v0.z * inv * g0.z, v0.w * inv * g0.w,
                 v1.x * inv * g1.x, v1.y * inv * g1.y,
                 v1.z * inv * g1.z, v1.w * inv * g1.w};
  ushort4 p0, p1;
  __hip_bfloat16 t;
  t = __float2bfloat16(ov[0]); p0.x = *(unsigned short*)&t;
  t = __float2bfloat16(ov[1]); p0.y = *(unsigned short*)&t;
  t = __float2bfloat16(ov[2]); p0.z = *(unsigned short*)&t;
  t = __float2bfloat16(ov[3]); p0.w = *(unsigned short*)&t;
  t = __float2bfloat16(ov[4]); p1.x = *(unsigned short*)&t;
  t = __float2bfloat16(ov[5]); p1.y = *(unsigned short*)&t;
  t = __float2bfloat16(ov[6]); p1.z = *(unsigned short*)&t;
  t = __float2bfloat16(ov[7]); p1.w = *(unsigned short*)&t;
  ushort4* op = (ushort4*)(O + row * 2048 + tid * 8);
  op[0] = p0;
  op[1] = p1;
}

// ------------------------------- launch -------------------------------------
extern "C" void kernel_launch(void* const* d_in, const int* in_sizes, int n_in,
                              void* d_out, int out_size, void* d_ws,
                              size_t ws_size, hipStream_t stream) {
  const float* x     = (const float*)d_in[0];  // (4,2048,2048)
  const float* w_in  = (const float*)d_in[1];  // (2048,2048)
  const float* b_in  = (const float*)d_in[2];  // (2048,)
  const float* w_st  = (const float*)d_in[3];  // (32,64,64)
  const float* nw    = (const float*)d_in[4];  // (2048,)
  const float* w_out = (const float*)d_in[5];  // (2048,2048)
  float* out = (float*)d_out;

  char* ws = (char*)d_ws;
  __hip_bfloat16* x_bf  = (__hip_bfloat16*)(ws);              // 33,554,432 B
  __hip_bfloat16* wi_bf = (__hip_bfloat16*)(ws + 33554432);   //  8,388,608 B
  __hip_bfloat16* wo_bf = (__hip_bfloat16*)(ws + 41943040);   //  8,388,608 B
  float* h              = (float*)(ws + 50331648);            // 67,108,864 B
  // x_bf buffer is reused for the rmsnorm'ed bf16 states (same size).

  cvt_f32_bf16<<<16384, 256, 0, stream>>>(x, x_bf, 4194304);
  cvt_f32_bf16<<<4096, 256, 0, stream>>>(w_in, wi_bf, 1048576);
  cvt_f32_bf16<<<4096, 256, 0, stream>>>(w_out, wo_bf, 1048576);

  // h = x @ w_in^T + b_in   (M=8192, N=2048, K=2048)
  gemm_nt<<<dim3(16, 64), 256, 0, stream>>>(x_bf, wi_bf, b_in, h,
                                            8192, 2048, 2048);
  // in-place tanh recurrence per (batch, head)
  scan_kernel<<<128, 64, 0, stream>>>(w_st, h);
  // rmsnorm + cast to bf16 (into x_bf buffer)
  rmsnorm_to_bf16<<<8192, 256, 0, stream>>>(h, nw, x_bf);
  // out = y_norm @ w_out^T
  gemm_nt<<<dim3(16, 64), 256, 0, stream>>>(x_bf, wo_bf, nullptr, out,
                                            8192, 2048, 2048);
}

// Round 2
// 819.421 us; speedup vs baseline: 1.3116x; 1.3116x over previous
//
#include <hip/hip_runtime.h>
#include <hip/hip_bf16.h>
#include <cstdint>

// ---------------------------------------------------------------------------
// RNN_11828339933262: h = x @ w_in^T + b_in ; s_t = tanh(s_{t-1} @ W_n + h_t)
//                     y = rmsnorm(s) * norm_weight ; out = y @ w_out^T
// B=4 S=2048 D=2048 N_HEADS=32 HD=64.  All I/O f32; internal GEMMs bf16 MFMA.
// R2: scan rewritten — no __syncthreads (single-wave block, explicit
// s_waitcnt lgkmcnt(0) between LDS write and broadcast reads), packed
// v_pk_fma_f32 for the 64-term dot, double-buffered x prefetch.
// ---------------------------------------------------------------------------

typedef short bf16x8 __attribute__((ext_vector_type(8)));   // 8 bf16 = 4 VGPRs
typedef float f32x4 __attribute__((ext_vector_type(4)));
typedef float f32x2 __attribute__((ext_vector_type(2)));

#define GLD16(gp, lp)                                                          \
  __builtin_amdgcn_global_load_lds(                                            \
      (const __attribute__((address_space(1))) void*)(gp),                     \
      (__attribute__((address_space(3))) void*)(lp), 16, 0, 0)

// ---------------------------- f32 -> bf16 convert --------------------------
__global__ __launch_bounds__(256) void cvt_f32_bf16(
    const float* __restrict__ in, __hip_bfloat16* __restrict__ out, int n4) {
  int i = blockIdx.x * 256 + threadIdx.x;
  if (i >= n4) return;
  float4 v = ((const float4*)in)[i];
  __hip_bfloat16 a = __float2bfloat16(v.x);
  __hip_bfloat16 b = __float2bfloat16(v.y);
  __hip_bfloat16 c = __float2bfloat16(v.z);
  __hip_bfloat16 d = __float2bfloat16(v.w);
  ushort4 p;
  p.x = *(unsigned short*)&a; p.y = *(unsigned short*)&b;
  p.z = *(unsigned short*)&c; p.w = *(unsigned short*)&d;
  ((ushort4*)out)[i] = p;
}

// ------------------------------- NT GEMM ------------------------------------
// C[M][N] = sum_k A[m][k]*B[n][k] (+bias[n]).  A,B bf16 row-major K-contig.
// 128x128 block tile, BK=32, 256 threads = 4 waves in 2x2, each wave 64x64
// (4x4 tiles of mfma_f32_16x16x32_bf16).  m97 structure.
__global__ __launch_bounds__(256) void gemm_nt(
    const __hip_bfloat16* __restrict__ A, const __hip_bfloat16* __restrict__ B,
    const float* __restrict__ bias, float* __restrict__ C,
    int M, int N, int K) {
  __shared__ __hip_bfloat16 As[128 * 32];
  __shared__ __hip_bfloat16 Bs[128 * 32];
  const int tid  = threadIdx.x;
  const int lane = tid & 63;
  const int wave = tid >> 6;
  const int wm = wave >> 1, wn = wave & 1;
  const long bm = (long)blockIdx.y * 128;
  const long bn = (long)blockIdx.x * 128;

  const int c0 = tid, c1 = tid + 256;
  const int r0 = c0 >> 2, k0 = (c0 & 3) * 8;
  const int r1 = c1 >> 2, k1 = (c1 & 3) * 8;
  __hip_bfloat16* lA0 = &As[(wave * 64) * 8];
  __hip_bfloat16* lA1 = &As[(256 + wave * 64) * 8];
  __hip_bfloat16* lB0 = &Bs[(wave * 64) * 8];
  __hip_bfloat16* lB1 = &Bs[(256 + wave * 64) * 8];
  const __hip_bfloat16* gA0 = A + (bm + r0) * (long)K + k0;
  const __hip_bfloat16* gA1 = A + (bm + r1) * (long)K + k1;
  const __hip_bfloat16* gB0 = B + (bn + r0) * (long)K + k0;
  const __hip_bfloat16* gB1 = B + (bn + r1) * (long)K + k1;

  const int fr = lane & 15;
  const int fk = (lane >> 4) * 8;

  f32x4 acc[4][4];
#pragma unroll
  for (int i = 0; i < 4; i++)
#pragma unroll
    for (int j = 0; j < 4; j++) acc[i][j] = {0.f, 0.f, 0.f, 0.f};

  for (int kt = 0; kt < K; kt += 32) {
    __syncthreads();
    GLD16(gA0 + kt, lA0);
    GLD16(gA1 + kt, lA1);
    GLD16(gB0 + kt, lB0);
    GLD16(gB1 + kt, lB1);
    __syncthreads();
    bf16x8 af[4], bfr[4];
#pragma unroll
    for (int t = 0; t < 4; t++)
      af[t] = *(const bf16x8*)&As[(wm * 64 + t * 16 + fr) * 32 + fk];
#pragma unroll
    for (int t = 0; t < 4; t++)
      bfr[t] = *(const bf16x8*)&Bs[(wn * 64 + t * 16 + fr) * 32 + fk];
#pragma unroll
    for (int i = 0; i < 4; i++)
#pragma unroll
      for (int j = 0; j < 4; j++)
        acc[i][j] = __builtin_amdgcn_mfma_f32_16x16x32_bf16(
            af[i], bfr[j], acc[i][j], 0, 0, 0);
  }

  const int cr = (lane >> 4) * 4;
  const int cc = lane & 15;
#pragma unroll
  for (int j = 0; j < 4; j++) {
    const long n = bn + wn * 64 + j * 16 + cc;
    const float bv = bias ? bias[n] : 0.0f;
#pragma unroll
    for (int i = 0; i < 4; i++) {
      const long m = bm + wm * 64 + i * 16 + cr;
#pragma unroll
      for (int r = 0; r < 4; r++)
        C[(m + r) * (long)N + n] = acc[i][j][r] + bv;
    }
  }
}

// ------------------------------- RNN scan -----------------------------------
// One wave per (batch, head) chain; lane k owns output k. W column packed as
// 32 f32x2 in VGPRs. State broadcast via 64-float LDS buffer; single-wave
// block -> no s_barrier, just s_waitcnt lgkmcnt(0) between write and reads
// (DS ops from one wave complete in order). Global stores are fire-and-forget.
__device__ __forceinline__ void pk_fma(f32x2& d, f32x2 a, f32x2 b) {
  asm("v_pk_fma_f32 %0, %1, %2, %0" : "+v"(d) : "v"(a), "v"(b));
}

__device__ __forceinline__ float tanh_fast(float z) {
  float e = __expf(2.0f * z);
  return 1.0f - 2.0f * __builtin_amdgcn_rcpf(e + 1.0f);
}

__global__ __launch_bounds__(64) void scan_kernel(
    const float* __restrict__ Wst, float* __restrict__ h) {
  const int b = blockIdx.x >> 5;    // 0..3
  const int n = blockIdx.x & 31;    // 0..31
  const int lane = threadIdx.x;     // 0..63
  const float* Wn = Wst + n * 4096; // W[n][h][k], k contiguous
  f32x2 w2[32];
#pragma unroll
  for (int j = 0; j < 32; j++) {
    f32x2 t;
    t.x = Wn[(2 * j) * 64 + lane];
    t.y = Wn[(2 * j + 1) * 64 + lane];
    w2[j] = t;
  }

  __shared__ float s_lds[64];

  float4 sv[16];
#pragma unroll
  for (int i = 0; i < 16; i++) sv[i] = make_float4(0.f, 0.f, 0.f, 0.f);

  float* hp = h + ((size_t)b * 2048) * 2048 + n * 64 + lane;  // t-stride 2048
  float xcur[8], xnxt[8];
#pragma unroll
  for (int i = 0; i < 8; i++) xcur[i] = hp[(size_t)i * 2048];

  for (int t0 = 0; t0 < 2048; t0 += 8) {
    if (t0 + 8 < 2048) {
#pragma unroll
      for (int i = 0; i < 8; i++)
        xnxt[i] = hp[(size_t)(t0 + 8 + i) * 2048];
    }
#pragma unroll
    for (int i = 0; i < 8; i++) {
      f32x2 acc[4];
      acc[0].x = xcur[i]; acc[0].y = 0.f;
      acc[1] = acc[2] = acc[3] = f32x2{0.f, 0.f};
#pragma unroll
      for (int q = 0; q < 16; q++) {
        f32x2 lo; lo.x = sv[q].x; lo.y = sv[q].y;
        f32x2 hi; hi.x = sv[q].z; hi.y = sv[q].w;
        pk_fma(acc[(2 * q) & 3], lo, w2[2 * q]);
        pk_fma(acc[(2 * q + 1) & 3], hi, w2[2 * q + 1]);
      }
      f32x2 s01 = acc[0] + acc[1];
      f32x2 s23 = acc[2] + acc[3];
      f32x2 st = s01 + s23;
      float sn = tanh_fast(st.x + st.y);
      hp[(size_t)(t0 + i) * 2048] = sn;   // fire-and-forget
      s_lds[lane] = sn;
      asm volatile("s_waitcnt lgkmcnt(0)" ::: "memory");
#pragma unroll
      for (int q = 0; q < 16; q++) sv[q] = ((const float4*)s_lds)[q];
    }
#pragma unroll
    for (int i = 0; i < 8; i++) xcur[i] = xnxt[i];
  }
}

// --------------------------- RMSNorm -> bf16 --------------------------------
__global__ __launch_bounds__(256) void rmsnorm_to_bf16(
    const float* __restrict__ Y, const float* __restrict__ g,
    __hip_bfloat16* __restrict__ O) {
  const long row = blockIdx.x;
  const float* yr = Y + row * 2048;
  const int tid = threadIdx.x;
  float4 v0 = ((const float4*)yr)[tid * 2];
  float4 v1 = ((const float4*)yr)[tid * 2 + 1];
  float ss = v0.x * v0.x + v0.y * v0.y + v0.z * v0.z + v0.w * v0.w +
             v1.x * v1.x + v1.y * v1.y + v1.z * v1.z + v1.w * v1.w;
#pragma unroll
  for (int off = 32; off > 0; off >>= 1) ss += __shfl_down(ss, off);
  __shared__ float red[4];
  if ((tid & 63) == 0) red[tid >> 6] = ss;
  __syncthreads();
  float inv = rsqrtf((red[0] + red[1] + red[2] + red[3]) * (1.0f / 2048.0f)
                     + 1e-6f);
  float4 g0 = ((const float4*)(g + tid * 8))[0];
  float4 g1 = ((const float4*)(g + tid * 8))[1];
  float ov[8] = {v0.x * inv * g0.x, v0.y * inv * g0.y,
                 v0.z * inv * g0.z, v0.w * inv * g0.w,
                 v1.x * inv * g1.x, v1.y * inv * g1.y,
                 v1.z * inv * g1.z, v1.w * inv * g1.w};
  ushort4 p0, p1;
  __hip_bfloat16 t;
  t = __float2bfloat16(ov[0]); p0.x = *(unsigned short*)&t;
  t = __float2bfloat16(ov[1]); p0.y = *(unsigned short*)&t;
  t = __float2bfloat16(ov[2]); p0.z = *(unsigned short*)&t;
  t = __float2bfloat16(ov[3]); p0.w = *(unsigned short*)&t;
  t = __float2bfloat16(ov[4]); p1.x = *(unsigned short*)&t;
  t = __float2bfloat16(ov[5]); p1.y = *(unsigned short*)&t;
  t = __float2bfloat16(ov[6]); p1.z = *(unsigned short*)&t;
  t = __float2bfloat16(ov[7]); p1.w = *(unsigned short*)&t;
  ushort4* op = (ushort4*)(O + row * 2048 + tid * 8);
  op[0] = p0;
  op[1] = p1;
}

// ------------------------------- launch -------------------------------------
extern "C" void kernel_launch(void* const* d_in, const int* in_sizes, int n_in,
                              void* d_out, int out_size, void* d_ws,
                              size_t ws_size, hipStream_t stream) {
  const float* x     = (const float*)d_in[0];  // (4,2048,2048)
  const float* w_in  = (const float*)d_in[1];  // (2048,2048)
  const float* b_in  = (const float*)d_in[2];  // (2048,)
  const float* w_st  = (const float*)d_in[3];  // (32,64,64)
  const float* nw    = (const float*)d_in[4];  // (2048,)
  const float* w_out = (const float*)d_in[5];  // (2048,2048)
  float* out = (float*)d_out;

  char* ws = (char*)d_ws;
  __hip_bfloat16* x_bf  = (__hip_bfloat16*)(ws);              // 33,554,432 B
  __hip_bfloat16* wi_bf = (__hip_bfloat16*)(ws + 33554432);   //  8,388,608 B
  __hip_bfloat16* wo_bf = (__hip_bfloat16*)(ws + 41943040);   //  8,388,608 B
  float* h              = (float*)(ws + 50331648);            // 67,108,864 B
  // x_bf buffer is reused for the rmsnorm'ed bf16 states (same size).

  cvt_f32_bf16<<<16384, 256, 0, stream>>>(x, x_bf, 4194304);
  cvt_f32_bf16<<<4096, 256, 0, stream>>>(w_in, wi_bf, 1048576);
  cvt_f32_bf16<<<4096, 256, 0, stream>>>(w_out, wo_bf, 1048576);

  // h = x @ w_in^T + b_in   (M=8192, N=2048, K=2048)
  gemm_nt<<<dim3(16, 64), 256, 0, stream>>>(x_bf, wi_bf, b_in, h,
                                            8192, 2048, 2048);
  // in-place tanh recurrence per (batch, head)
  scan_kernel<<<128, 64, 0, stream>>>(w_st, h);
  // rmsnorm + cast to bf16 (into x_bf buffer)
  rmsnorm_to_bf16<<<8192, 256, 0, stream>>>(h, nw, x_bf);
  // out = y_norm @ w_out^T
  gemm_nt<<<dim3(16, 64), 256, 0, stream>>>(x_bf, wo_bf, nullptr, out,
                                            8192, 2048, 2048);
}

// Round 3
// 795.270 us; speedup vs baseline: 1.3515x; 1.0304x over previous
//
#include <hip/hip_runtime.h>
#include <hip/hip_bf16.h>
#include <cstdint>

// ---------------------------------------------------------------------------
// RNN_11828339933262: h = x @ w_in^T + b_in ; s_t = tanh(s_{t-1} @ W_n + h_t)
//                     y = rmsnorm(s) * norm_weight ; out = y @ w_out^T
// B=4 S=2048 D=2048 N_HEADS=32 HD=64.  All I/O f32; internal GEMMs bf16 MFMA.
// R3: scan — rely on in-order DS pipe (NO waitcnt between ds_write and the 16
// broadcast ds_read_b128; compiler emits fine-grained lgkmcnt before uses so
// the 32 pk_fma issue hides inside the LDS latency window). Loop rotated:
// reads for step t+1 issued at tail of step t, global store after DS ops.
// ---------------------------------------------------------------------------

typedef short bf16x8 __attribute__((ext_vector_type(8)));   // 8 bf16 = 4 VGPRs
typedef float f32x4 __attribute__((ext_vector_type(4)));
typedef float f32x2 __attribute__((ext_vector_type(2)));

#define GLD16(gp, lp)                                                          \
  __builtin_amdgcn_global_load_lds(                                            \
      (const __attribute__((address_space(1))) void*)(gp),                     \
      (__attribute__((address_space(3))) void*)(lp), 16, 0, 0)

// ---------------------------- f32 -> bf16 convert --------------------------
__global__ __launch_bounds__(256) void cvt_f32_bf16(
    const float* __restrict__ in, __hip_bfloat16* __restrict__ out, int n4) {
  int i = blockIdx.x * 256 + threadIdx.x;
  if (i >= n4) return;
  float4 v = ((const float4*)in)[i];
  __hip_bfloat16 a = __float2bfloat16(v.x);
  __hip_bfloat16 b = __float2bfloat16(v.y);
  __hip_bfloat16 c = __float2bfloat16(v.z);
  __hip_bfloat16 d = __float2bfloat16(v.w);
  ushort4 p;
  p.x = *(unsigned short*)&a; p.y = *(unsigned short*)&b;
  p.z = *(unsigned short*)&c; p.w = *(unsigned short*)&d;
  ((ushort4*)out)[i] = p;
}

// ------------------------------- NT GEMM ------------------------------------
__global__ __launch_bounds__(256) void gemm_nt(
    const __hip_bfloat16* __restrict__ A, const __hip_bfloat16* __restrict__ B,
    const float* __restrict__ bias, float* __restrict__ C,
    int M, int N, int K) {
  __shared__ __hip_bfloat16 As[128 * 32];
  __shared__ __hip_bfloat16 Bs[128 * 32];
  const int tid  = threadIdx.x;
  const int lane = tid & 63;
  const int wave = tid >> 6;
  const int wm = wave >> 1, wn = wave & 1;
  const long bm = (long)blockIdx.y * 128;
  const long bn = (long)blockIdx.x * 128;

  const int c0 = tid, c1 = tid + 256;
  const int r0 = c0 >> 2, k0 = (c0 & 3) * 8;
  const int r1 = c1 >> 2, k1 = (c1 & 3) * 8;
  __hip_bfloat16* lA0 = &As[(wave * 64) * 8];
  __hip_bfloat16* lA1 = &As[(256 + wave * 64) * 8];
  __hip_bfloat16* lB0 = &Bs[(wave * 64) * 8];
  __hip_bfloat16* lB1 = &Bs[(256 + wave * 64) * 8];
  const __hip_bfloat16* gA0 = A + (bm + r0) * (long)K + k0;
  const __hip_bfloat16* gA1 = A + (bm + r1) * (long)K + k1;
  const __hip_bfloat16* gB0 = B + (bn + r0) * (long)K + k0;
  const __hip_bfloat16* gB1 = B + (bn + r1) * (long)K + k1;

  const int fr = lane & 15;
  const int fk = (lane >> 4) * 8;

  f32x4 acc[4][4];
#pragma unroll
  for (int i = 0; i < 4; i++)
#pragma unroll
    for (int j = 0; j < 4; j++) acc[i][j] = {0.f, 0.f, 0.f, 0.f};

  for (int kt = 0; kt < K; kt += 32) {
    __syncthreads();
    GLD16(gA0 + kt, lA0);
    GLD16(gA1 + kt, lA1);
    GLD16(gB0 + kt, lB0);
    GLD16(gB1 + kt, lB1);
    __syncthreads();
    bf16x8 af[4], bfr[4];
#pragma unroll
    for (int t = 0; t < 4; t++)
      af[t] = *(const bf16x8*)&As[(wm * 64 + t * 16 + fr) * 32 + fk];
#pragma unroll
    for (int t = 0; t < 4; t++)
      bfr[t] = *(const bf16x8*)&Bs[(wn * 64 + t * 16 + fr) * 32 + fk];
#pragma unroll
    for (int i = 0; i < 4; i++)
#pragma unroll
      for (int j = 0; j < 4; j++)
        acc[i][j] = __builtin_amdgcn_mfma_f32_16x16x32_bf16(
            af[i], bfr[j], acc[i][j], 0, 0, 0);
  }

  const int cr = (lane >> 4) * 4;
  const int cc = lane & 15;
#pragma unroll
  for (int j = 0; j < 4; j++) {
    const long n = bn + wn * 64 + j * 16 + cc;
    const float bv = bias ? bias[n] : 0.0f;
#pragma unroll
    for (int i = 0; i < 4; i++) {
      const long m = bm + wm * 64 + i * 16 + cr;
#pragma unroll
      for (int r = 0; r < 4; r++)
        C[(m + r) * (long)N + n] = acc[i][j][r] + bv;
    }
  }
}

// ------------------------------- RNN scan -----------------------------------
// One wave per (batch, head) chain; lane k owns output k. W column packed as
// 32 f32x2 in VGPRs. State broadcast via 64-float LDS buffer. Single-wave
// block + in-order DS pipe -> NO waitcnt between the write and the broadcast
// reads; compiler gates each pk_fma on its read with fine-grained lgkmcnt,
// so the 64-cycle FMA issue hides inside the DS latency window.
__device__ __forceinline__ void pk_fma(f32x2& d, f32x2 a, f32x2 b) {
  asm("v_pk_fma_f32 %0, %1, %2, %0" : "+v"(d) : "v"(a), "v"(b));
}

__device__ __forceinline__ float tanh_fast(float z) {
  float e = __expf(2.0f * z);
  return 1.0f - 2.0f * __builtin_amdgcn_rcpf(e + 1.0f);
}

__global__ __launch_bounds__(64) void scan_kernel(
    const float* __restrict__ Wst, float* __restrict__ h) {
  const int b = blockIdx.x >> 5;    // 0..3
  const int n = blockIdx.x & 31;    // 0..31
  const int lane = threadIdx.x;     // 0..63
  const float* Wn = Wst + n * 4096; // W[n][h][k], k contiguous
  f32x2 w2[32];
#pragma unroll
  for (int j = 0; j < 32; j++) {
    f32x2 t;
    t.x = Wn[(2 * j) * 64 + lane];
    t.y = Wn[(2 * j + 1) * 64 + lane];
    w2[j] = t;
  }

  __shared__ float s_lds[64];

  // State fragments for the *upcoming* step; s_0 = 0 so start at zero
  // (each step writes s_lds before reading, so no priming write needed).
  float4 sv[16];
#pragma unroll
  for (int i = 0; i < 16; i++) sv[i] = make_float4(0.f, 0.f, 0.f, 0.f);

  float* hp = h + ((size_t)b * 2048) * 2048 + n * 64 + lane;  // t-stride 2048
  float xcur[8], xnxt[8];
#pragma unroll
  for (int i = 0; i < 8; i++) xcur[i] = hp[(size_t)i * 2048];

  for (int t0 = 0; t0 < 2048; t0 += 8) {
    if (t0 + 8 < 2048) {
#pragma unroll
      for (int i = 0; i < 8; i++)
        xnxt[i] = hp[(size_t)(t0 + 8 + i) * 2048];
    }
#pragma unroll
    for (int i = 0; i < 8; i++) {
      // dot(s_{t-1}, W[:,lane]) + x_t  — consumes sv[q] in read order so the
      // compiler's progressive lgkmcnt lets FMAs start as reads land.
      f32x2 acc[4];
      acc[0].x = xcur[i]; acc[0].y = 0.f;
      acc[1] = acc[2] = acc[3] = f32x2{0.f, 0.f};
#pragma unroll
      for (int q = 0; q < 16; q++) {
        f32x2 lo; lo.x = sv[q].x; lo.y = sv[q].y;
        f32x2 hi; hi.x = sv[q].z; hi.y = sv[q].w;
        pk_fma(acc[(2 * q) & 3], lo, w2[2 * q]);
        pk_fma(acc[(2 * q + 1) & 3], hi, w2[2 * q + 1]);
      }
      f32x2 s01 = acc[0] + acc[1];
      f32x2 s23 = acc[2] + acc[3];
      f32x2 st = s01 + s23;
      float sn = tanh_fast(st.x + st.y);
      // Broadcast s_t for step t+1: write then immediately issue all 16
      // reads — DS pipe is in-order per wave, no waitcnt needed between.
      s_lds[lane] = sn;
#pragma unroll
      for (int q = 0; q < 16; q++) sv[q] = ((const float4*)s_lds)[q];
      hp[(size_t)(t0 + i) * 2048] = sn;   // fire-and-forget, off the path
    }
#pragma unroll
    for (int i = 0; i < 8; i++) xcur[i] = xnxt[i];
  }
}

// --------------------------- RMSNorm -> bf16 --------------------------------
__global__ __launch_bounds__(256) void rmsnorm_to_bf16(
    const float* __restrict__ Y, const float* __restrict__ g,
    __hip_bfloat16* __restrict__ O) {
  const long row = blockIdx.x;
  const float* yr = Y + row * 2048;
  const int tid = threadIdx.x;
  float4 v0 = ((const float4*)yr)[tid * 2];
  float4 v1 = ((const float4*)yr)[tid * 2 + 1];
  float ss = v0.x * v0.x + v0.y * v0.y + v0.z * v0.z + v0.w * v0.w +
             v1.x * v1.x + v1.y * v1.y + v1.z * v1.z + v1.w * v1.w;
#pragma unroll
  for (int off = 32; off > 0; off >>= 1) ss += __shfl_down(ss, off);
  __shared__ float red[4];
  if ((tid & 63) == 0) red[tid >> 6] = ss;
  __syncthreads();
  float inv = rsqrtf((red[0] + red[1] + red[2] + red[3]) * (1.0f / 2048.0f)
                     + 1e-6f);
  float4 g0 = ((const float4*)(g + tid * 8))[0];
  float4 g1 = ((const float4*)(g + tid * 8))[1];
  float ov[8] = {v0.x * inv * g0.x, v0.y * inv * g0.y,
                 v0.z * inv * g0.z, v0.w * inv * g0.w,
                 v1.x * inv * g1.x, v1.y * inv * g1.y,
                 v1.z * inv * g1.z, v1.w * inv * g1.w};
  ushort4 p0, p1;
  __hip_bfloat16 t;
  t = __float2bfloat16(ov[0]); p0.x = *(unsigned short*)&t;
  t = __float2bfloat16(ov[1]); p0.y = *(unsigned short*)&t;
  t = __float2bfloat16(ov[2]); p0.z = *(unsigned short*)&t;
  t = __float2bfloat16(ov[3]); p0.w = *(unsigned short*)&t;
  t = __float2bfloat16(ov[4]); p1.x = *(unsigned short*)&t;
  t = __float2bfloat16(ov[5]); p1.y = *(unsigned short*)&t;
  t = __float2bfloat16(ov[6]); p1.z = *(unsigned short*)&t;
  t = __float2bfloat16(ov[7]); p1.w = *(unsigned short*)&t;
  ushort4* op = (ushort4*)(O + row * 2048 + tid * 8);
  op[0] = p0;
  op[1] = p1;
}

// ------------------------------- launch -------------------------------------
extern "C" void kernel_launch(void* const* d_in, const int* in_sizes, int n_in,
                              void* d_out, int out_size, void* d_ws,
                              size_t ws_size, hipStream_t stream) {
  const float* x     = (const float*)d_in[0];  // (4,2048,2048)
  const float* w_in  = (const float*)d_in[1];  // (2048,2048)
  const float* b_in  = (const float*)d_in[2];  // (2048,)
  const float* w_st  = (const float*)d_in[3];  // (32,64,64)
  const float* nw    = (const float*)d_in[4];  // (2048,)
  const float* w_out = (const float*)d_in[5];  // (2048,2048)
  float* out = (float*)d_out;

  char* ws = (char*)d_ws;
  __hip_bfloat16* x_bf  = (__hip_bfloat16*)(ws);              // 33,554,432 B
  __hip_bfloat16* wi_bf = (__hip_bfloat16*)(ws + 33554432);   //  8,388,608 B
  __hip_bfloat16* wo_bf = (__hip_bfloat16*)(ws + 41943040);   //  8,388,608 B
  float* h              = (float*)(ws + 50331648);            // 67,108,864 B
  // x_bf buffer is reused for the rmsnorm'ed bf16 states (same size).

  cvt_f32_bf16<<<16384, 256, 0, stream>>>(x, x_bf, 4194304);
  cvt_f32_bf16<<<4096, 256, 0, stream>>>(w_in, wi_bf, 1048576);
  cvt_f32_bf16<<<4096, 256, 0, stream>>>(w_out, wo_bf, 1048576);

  // h = x @ w_in^T + b_in   (M=8192, N=2048, K=2048)
  gemm_nt<<<dim3(16, 64), 256, 0, stream>>>(x_bf, wi_bf, b_in, h,
                                            8192, 2048, 2048);
  // in-place tanh recurrence per (batch, head)
  scan_kernel<<<128, 64, 0, stream>>>(w_st, h);
  // rmsnorm + cast to bf16 (into x_bf buffer)
  rmsnorm_to_bf16<<<8192, 256, 0, stream>>>(h, nw, x_bf);
  // out = y_norm @ w_out^T
  gemm_nt<<<dim3(16, 64), 256, 0, stream>>>(x_bf, wo_bf, nullptr, out,
                                            8192, 2048, 2048);
}